// Round 7
// baseline (158.125 us; speedup 1.0000x reference)
//
#include <hip/hip_runtime.h>

typedef __attribute__((ext_vector_type(8))) short bf16x8;
typedef __attribute__((ext_vector_type(4))) float f32x4;

#define NB 1024
#define NC 64
#define NT 512
#define ND 32

__device__ __forceinline__ unsigned short f2bf(float f) {
  unsigned u = __float_as_uint(f);
  u += 0x7FFFu + ((u >> 16) & 1u);   // round-to-nearest-even (finite values)
  return (unsigned short)(u >> 16);
}
__device__ __forceinline__ float bf2f(unsigned short h) {
  return __uint_as_float(((unsigned)h) << 16);
}

// ---- prep: rearrange weights into MFMA B-fragment order (bf16) ----
// ws layout (ushort elements):
//   [0,16384)      Win  frags [ks(16)][nt(2)][lane(64)][j(8)]   B[k][n], k=32ks+8(l>>4)+j, n=16nt+(l&15)
//   [16384,32768)  Wout frags [nt(32)][lane(64)][j(8)]
//   [32768,33792)  Wq   frags [nt(2)][lane(64)][j(8)]
//   [33792,34816)  Wk   frags
//   [34816,35840)  Wv   frags
__global__ void prep_weights(const float* __restrict__ Win, const float* __restrict__ Wq,
                             const float* __restrict__ Wk, const float* __restrict__ Wv,
                             const float* __restrict__ Wout, unsigned short* __restrict__ ws) {
  int idx = blockIdx.x * 256 + threadIdx.x;
  if (idx >= 35840) return;
  float v;
  if (idx < 16384) {
    int j = idx & 7, lane = (idx >> 3) & 63, nt = (idx >> 9) & 1, ks = idx >> 10;
    int t = 32 * ks + 8 * (lane >> 4) + j;
    int d = 16 * nt + (lane & 15);
    v = Win[t * ND + d];
  } else if (idx < 32768) {
    int p = idx - 16384;
    int j = p & 7, lane = (p >> 3) & 63, nt = (p >> 9) & 31;
    int k = 8 * (lane >> 4) + j;
    int n = 16 * nt + (lane & 15);
    v = Wout[k * NT + n];
  } else {
    int p = idx - 32768;
    const float* W = (p < 1024) ? Wq : ((p < 2048) ? Wk : Wv);
    int q = p & 1023;
    int j = q & 7, lane = (q >> 3) & 63, nt = (q >> 9) & 1;
    int t = 8 * (lane >> 4) + j;
    int d = 16 * nt + (lane & 15);
    v = W[t * ND + d];
  }
  ws[idx] = f2bf(v);
}

// ---- fused main kernel: one block per batch, 256 threads (4 waves) ----
// Register budget: <=128 unified -> 4 waves/SIMD -> 4 blocks/CU.
// P3: online no-max softmax (scores |s|<~3, exp2 f32-safe) -> no score array.
// P4: SINGLE pass. Wave w owns row-tile w (16 rows) x all 512 cols; thread owns
//     4 rows x 32 col-chunks. y kept packed bf16 in 64 u32 regs (static-indexed,
//     both loops fully unrolled); pass 2 = unpack+normalize+store, no loads/MFMA.
// LDS = 4096 (h/o frags) + 27648 (q/k/v f32) = 31744 B.
__global__ __launch_bounds__(256, 4)
void mha_main(const float* __restrict__ x, const float* __restrict__ b_in,
              const float* __restrict__ b_out, const float* __restrict__ gamma,
              const float* __restrict__ beta, const unsigned short* __restrict__ wsb,
              float* __restrict__ out) {
  __shared__ __align__(16) unsigned short lds_ho[4][64][8];  // h frags, then o frags
  __shared__ __align__(16) float lds_q[64][36];
  __shared__ __align__(16) float lds_k[64][36];
  __shared__ __align__(16) float lds_v[64][36];

  const int tid = threadIdx.x;
  const int w  = tid >> 6;   // wave id
  const int l  = tid & 63;   // lane
  const int g  = l >> 4;     // quarter-wave group
  const int lo = l & 15;
  const int b  = blockIdx.x;
  const float* __restrict__ xb = x + (size_t)b * (NC * NT);

  // ---------------- P1: h = x @ W_in + b_in  (A-frags loaded from global) -------
  const int srow = 16 * w + lo;
  const float* __restrict__ xr = xb + srow * NT + 8 * g;
  const bf16x8* __restrict__ wsWin = (const bf16x8*)wsb;

  f32x4 zero4 = (f32x4){0.f, 0.f, 0.f, 0.f};
  f32x4 acc1[2];
  acc1[0] = zero4;
  acc1[1] = zero4;
  f32x4 ra = *(const f32x4*)(xr);
  f32x4 rb = *(const f32x4*)(xr + 4);
  bf16x8 bp0 = wsWin[l];
  bf16x8 bp1 = wsWin[64 + l];

#pragma unroll
  for (int ks = 0; ks < 16; ++ks) {
    bf16x8 af;
    af[0] = (short)f2bf(ra[0]); af[1] = (short)f2bf(ra[1]);
    af[2] = (short)f2bf(ra[2]); af[3] = (short)f2bf(ra[3]);
    af[4] = (short)f2bf(rb[0]); af[5] = (short)f2bf(rb[1]);
    af[6] = (short)f2bf(rb[2]); af[7] = (short)f2bf(rb[3]);
    int nk = (ks < 15) ? (ks + 1) : 15;   // prefetch next chunk (clamped)
    f32x4 ra2 = *(const f32x4*)(xr + 32 * nk);
    f32x4 rb2 = *(const f32x4*)(xr + 32 * nk + 4);
    bf16x8 bn0 = wsWin[(2 * nk) * 64 + l];
    bf16x8 bn1 = wsWin[(2 * nk + 1) * 64 + l];
    acc1[0] = __builtin_amdgcn_mfma_f32_16x16x32_bf16(af, bp0, acc1[0], 0, 0, 0);
    acc1[1] = __builtin_amdgcn_mfma_f32_16x16x32_bf16(af, bp1, acc1[1], 0, 0, 0);
    ra = ra2; rb = rb2; bp0 = bn0; bp1 = bn1;
  }

  float binv0 = b_in[lo];
  float binv1 = b_in[16 + lo];
  // D-frag: row = 16w + 4g + r, col = 16nt + lo  -> h into frag-direct LDS (bf16)
#pragma unroll
  for (int nt = 0; nt < 2; ++nt) {
#pragma unroll
    for (int r = 0; r < 4; ++r) {
      float hv = acc1[nt][r] + (nt ? binv1 : binv0);
      int cc = 2 * nt + (lo >> 3);
      int slotlane = (4 * g + r) | (cc << 4);
      lds_ho[w][slotlane][lo & 7] = f2bf(hv);
    }
  }
  __syncthreads();

  // ---------------- P2: q/k/v = h @ Wq/Wk/Wv  (6 MFMAs per wave) ----------------
  const bf16x8* __restrict__ wsWq = (const bf16x8*)(wsb + 32768);
  const bf16x8* __restrict__ wsWk = (const bf16x8*)(wsb + 33792);
  const bf16x8* __restrict__ wsWv = (const bf16x8*)(wsb + 34816);
  bf16x8 ah = *(const bf16x8*)&lds_ho[w][l][0];
  f32x4 qacc[2], kacc[2], vacc[2];
#pragma unroll
  for (int nt = 0; nt < 2; ++nt) {
    qacc[nt] = __builtin_amdgcn_mfma_f32_16x16x32_bf16(ah, wsWq[nt * 64 + l], zero4, 0, 0, 0);
    kacc[nt] = __builtin_amdgcn_mfma_f32_16x16x32_bf16(ah, wsWk[nt * 64 + l], zero4, 0, 0, 0);
    vacc[nt] = __builtin_amdgcn_mfma_f32_16x16x32_bf16(ah, wsWv[nt * 64 + l], zero4, 0, 0, 0);
  }
#pragma unroll
  for (int nt = 0; nt < 2; ++nt) {
#pragma unroll
    for (int r = 0; r < 4; ++r) {
      int row = 16 * w + 4 * g + r;
      int col = 16 * nt + lo;
      lds_q[row][col] = qacc[nt][r];
      lds_k[row][col] = kacc[nt][r];
      lds_v[row][col] = vacc[nt][r];
    }
  }
  __syncthreads();

  // ---------------- P3: attention, online no-max softmax ------------------------
  // thread = (channel c = lane, head = wave); scores |s| <~ 3 so exp2 is f32-safe
  {
    const int hd = w;
    const f32x4 qv0 = *(const f32x4*)&lds_q[l][8 * hd];
    const f32x4 qv1 = *(const f32x4*)&lds_q[l][8 * hd + 4];
    float sum = 0.f;
    float ov[8] = {0.f, 0.f, 0.f, 0.f, 0.f, 0.f, 0.f, 0.f};
#pragma unroll 4
    for (int kk = 0; kk < 64; ++kk) {
      f32x4 k0 = *(const f32x4*)&lds_k[kk][8 * hd];
      f32x4 k1 = *(const f32x4*)&lds_k[kk][8 * hd + 4];
      float s = qv0[0] * k0[0] + qv0[1] * k0[1] + qv0[2] * k0[2] + qv0[3] * k0[3]
              + qv1[0] * k1[0] + qv1[1] * k1[1] + qv1[2] * k1[2] + qv1[3] * k1[3];
      float p = exp2f(s * (1.4426950408889634f * 0.35355339059327373f));
      sum += p;
      f32x4 v0 = *(const f32x4*)&lds_v[kk][8 * hd];
      f32x4 v1 = *(const f32x4*)&lds_v[kk][8 * hd + 4];
      ov[0] += p * v0[0]; ov[1] += p * v0[1]; ov[2] += p * v0[2]; ov[3] += p * v0[3];
      ov[4] += p * v1[0]; ov[5] += p * v1[1]; ov[6] += p * v1[2]; ov[7] += p * v1[3];
    }
    float inv = 1.0f / sum;
    bf16x8 opk;
#pragma unroll
    for (int d = 0; d < 8; ++d) opk[d] = (short)f2bf(ov[d] * inv);
    // o[c][8hd+d] -> frag slot [c>>4][(c&15)|(hd<<4)][d]  (h is dead; reuse lds_ho)
    *(bf16x8*)&lds_ho[l >> 4][(l & 15) | (hd << 4)][0] = opk;
  }
  __syncthreads();

  // ---------------- P4: y = o @ W_out + b_out + x, LayerNorm (single pass) ------
  // wave w owns rows 16w..16w+15, ALL 512 cols; thread owns 4 rows (16w+4g+r).
  // y kept packed bf16 in registers: yp[nt][0]=rows 0,1  yp[nt][1]=rows 2,3.
  const bf16x8 a4 = *(const bf16x8*)&lds_ho[w][l][0];
  const bf16x8* __restrict__ wsWout = (const bf16x8*)(wsb + 16384);
  const int row0 = 16 * w + 4 * g;
  const float* __restrict__ xrow = xb + row0 * NT + lo;

  unsigned yp[32][2];
  float s1[4] = {0.f, 0.f, 0.f, 0.f};
  float s2[4] = {0.f, 0.f, 0.f, 0.f};

#pragma unroll
  for (int nt = 0; nt < 32; ++nt) {
    bf16x8 bfr = wsWout[nt * 64 + l];
    f32x4 acc = __builtin_amdgcn_mfma_f32_16x16x32_bf16(a4, bfr, zero4, 0, 0, 0);
    const int col = 16 * nt;
    float bo = b_out[col + lo];
    float y0 = acc[0] + bo + xrow[0 * NT + col];
    float y1 = acc[1] + bo + xrow[1 * NT + col];
    float y2 = acc[2] + bo + xrow[2 * NT + col];
    float y3 = acc[3] + bo + xrow[3 * NT + col];
    s1[0] += y0; s2[0] += y0 * y0;
    s1[1] += y1; s2[1] += y1 * y1;
    s1[2] += y2; s2[2] += y2 * y2;
    s1[3] += y3; s2[3] += y3 * y3;
    yp[nt][0] = (unsigned)f2bf(y0) | ((unsigned)f2bf(y1) << 16);
    yp[nt][1] = (unsigned)f2bf(y2) | ((unsigned)f2bf(y3) << 16);
  }
  // LN reduce: each row's 512 cols live in the 16 lanes sharing g
#pragma unroll
  for (int off = 1; off <= 8; off <<= 1) {
#pragma unroll
    for (int r = 0; r < 4; ++r) {
      s1[r] += __shfl_xor(s1[r], off, 64);
      s2[r] += __shfl_xor(s2[r], off, 64);
    }
  }
  float mu[4], rs[4];
#pragma unroll
  for (int r = 0; r < 4; ++r) {
    mu[r] = s1[r] * (1.0f / 512.0f);
    float var = s2[r] * (1.0f / 512.0f) - mu[r] * mu[r];
    rs[r] = rsqrtf(var + 1e-5f);
  }

  // ---- pass 2: unpack, normalize, store (no loads except gamma/beta, no MFMA) --
  float* __restrict__ orow = out + (size_t)b * (NC * NT) + row0 * NT + lo;
#pragma unroll
  for (int nt = 0; nt < 32; ++nt) {
    const int col = 16 * nt;
    float gm = gamma[col + lo];
    float bt = beta[col + lo];
    float y0 = bf2f((unsigned short)(yp[nt][0] & 0xffffu));
    float y1 = bf2f((unsigned short)(yp[nt][0] >> 16));
    float y2 = bf2f((unsigned short)(yp[nt][1] & 0xffffu));
    float y3 = bf2f((unsigned short)(yp[nt][1] >> 16));
    orow[0 * NT + col] = (y0 - mu[0]) * rs[0] * gm + bt;
    orow[1 * NT + col] = (y1 - mu[1]) * rs[1] * gm + bt;
    orow[2 * NT + col] = (y2 - mu[2]) * rs[2] * gm + bt;
    orow[3 * NT + col] = (y3 - mu[3]) * rs[3] * gm + bt;
  }
}

extern "C" void kernel_launch(void* const* d_in, const int* in_sizes, int n_in,
                              void* d_out, int out_size, void* d_ws, size_t ws_size,
                              hipStream_t stream) {
  const float* x     = (const float*)d_in[0];
  const float* W_in  = (const float*)d_in[1];
  const float* b_in  = (const float*)d_in[2];
  const float* W_q   = (const float*)d_in[3];
  const float* W_k   = (const float*)d_in[4];
  const float* W_v   = (const float*)d_in[5];
  const float* W_out = (const float*)d_in[6];
  const float* b_out = (const float*)d_in[7];
  const float* gamma = (const float*)d_in[8];
  const float* beta  = (const float*)d_in[9];
  unsigned short* ws = (unsigned short*)d_ws;

  prep_weights<<<140, 256, 0, stream>>>(W_in, W_q, W_k, W_v, W_out, ws);
  mha_main<<<NB, 256, 0, stream>>>(x, b_in, b_out, gamma, beta, ws, (float*)d_out);
}

// Round 8
// 137.032 us; speedup vs baseline: 1.1539x; 1.1539x over previous
//
#include <hip/hip_runtime.h>

typedef __attribute__((ext_vector_type(8))) short bf16x8;
typedef __attribute__((ext_vector_type(4))) float f32x4;

#define NB 1024
#define NC 64
#define NT 512
#define ND 32

__device__ __forceinline__ unsigned short f2bf(float f) {
  unsigned u = __float_as_uint(f);
  u += 0x7FFFu + ((u >> 16) & 1u);   // round-to-nearest-even (finite values)
  return (unsigned short)(u >> 16);
}
__device__ __forceinline__ float bf2f(unsigned short h) {
  return __uint_as_float(((unsigned)h) << 16);
}

// ---- prep: rearrange weights into MFMA B-fragment order (bf16) ----
// ws layout (ushort elements):
//   [0,16384)      Win  frags [ks(16)][nt(2)][lane(64)][j(8)]   B[k][n], k=32ks+8(l>>4)+j, n=16nt+(l&15)
//   [16384,32768)  Wout frags [nt(32)][lane(64)][j(8)]
//   [32768,33792)  Wq   frags [nt(2)][lane(64)][j(8)]
//   [33792,34816)  Wk   frags
//   [34816,35840)  Wv   frags
__global__ void prep_weights(const float* __restrict__ Win, const float* __restrict__ Wq,
                             const float* __restrict__ Wk, const float* __restrict__ Wv,
                             const float* __restrict__ Wout, unsigned short* __restrict__ ws) {
  int idx = blockIdx.x * 256 + threadIdx.x;
  if (idx >= 35840) return;
  float v;
  if (idx < 16384) {
    int j = idx & 7, lane = (idx >> 3) & 63, nt = (idx >> 9) & 1, ks = idx >> 10;
    int t = 32 * ks + 8 * (lane >> 4) + j;
    int d = 16 * nt + (lane & 15);
    v = Win[t * ND + d];
  } else if (idx < 32768) {
    int p = idx - 16384;
    int j = p & 7, lane = (p >> 3) & 63, nt = (p >> 9) & 31;
    int k = 8 * (lane >> 4) + j;
    int n = 16 * nt + (lane & 15);
    v = Wout[k * NT + n];
  } else {
    int p = idx - 32768;
    const float* W = (p < 1024) ? Wq : ((p < 2048) ? Wk : Wv);
    int q = p & 1023;
    int j = q & 7, lane = (q >> 3) & 63, nt = (q >> 9) & 1;
    int t = 8 * (lane >> 4) + j;
    int d = 16 * nt + (lane & 15);
    v = W[t * ND + d];
  }
  ws[idx] = f2bf(v);
}

// ---- fused main kernel: one block per batch, 256 threads (4 waves) ----
// Register budget: <=128 unified -> 4 waves/SIMD -> 4 blocks/CU.
// P3: online no-max softmax (scores |s|<~3, exp2 f32-safe) -> no score array.
// P4: SINGLE pass, y packed bf16 in 64 u32 regs (fully unrolled = static idx).
//     sched_barrier(0) every 4/8 iterations fences the scheduler's load
//     hoisting so liveness stays ~110 regs (R7 spilled without the fences).
// LDS = 4096 (h/o frags) + 27648 (q/k/v f32) = 31744 B.
__global__ __launch_bounds__(256, 4)
void mha_main(const float* __restrict__ x, const float* __restrict__ b_in,
              const float* __restrict__ b_out, const float* __restrict__ gamma,
              const float* __restrict__ beta, const unsigned short* __restrict__ wsb,
              float* __restrict__ out) {
  __shared__ __align__(16) unsigned short lds_ho[4][64][8];  // h frags, then o frags
  __shared__ __align__(16) float lds_q[64][36];
  __shared__ __align__(16) float lds_k[64][36];
  __shared__ __align__(16) float lds_v[64][36];

  const int tid = threadIdx.x;
  const int w  = tid >> 6;   // wave id
  const int l  = tid & 63;   // lane
  const int g  = l >> 4;     // quarter-wave group
  const int lo = l & 15;
  const int b  = blockIdx.x;
  const float* __restrict__ xb = x + (size_t)b * (NC * NT);

  // ---------------- P1: h = x @ W_in + b_in  (A-frags loaded from global) -------
  const int srow = 16 * w + lo;
  const float* __restrict__ xr = xb + srow * NT + 8 * g;
  const bf16x8* __restrict__ wsWin = (const bf16x8*)wsb;

  f32x4 zero4 = (f32x4){0.f, 0.f, 0.f, 0.f};
  f32x4 acc1[2];
  acc1[0] = zero4;
  acc1[1] = zero4;
  f32x4 ra = *(const f32x4*)(xr);
  f32x4 rb = *(const f32x4*)(xr + 4);
  bf16x8 bp0 = wsWin[l];
  bf16x8 bp1 = wsWin[64 + l];

#pragma unroll
  for (int ks = 0; ks < 16; ++ks) {
    bf16x8 af;
    af[0] = (short)f2bf(ra[0]); af[1] = (short)f2bf(ra[1]);
    af[2] = (short)f2bf(ra[2]); af[3] = (short)f2bf(ra[3]);
    af[4] = (short)f2bf(rb[0]); af[5] = (short)f2bf(rb[1]);
    af[6] = (short)f2bf(rb[2]); af[7] = (short)f2bf(rb[3]);
    int nk = (ks < 15) ? (ks + 1) : 15;   // prefetch next chunk (clamped)
    f32x4 ra2 = *(const f32x4*)(xr + 32 * nk);
    f32x4 rb2 = *(const f32x4*)(xr + 32 * nk + 4);
    bf16x8 bn0 = wsWin[(2 * nk) * 64 + l];
    bf16x8 bn1 = wsWin[(2 * nk + 1) * 64 + l];
    acc1[0] = __builtin_amdgcn_mfma_f32_16x16x32_bf16(af, bp0, acc1[0], 0, 0, 0);
    acc1[1] = __builtin_amdgcn_mfma_f32_16x16x32_bf16(af, bp1, acc1[1], 0, 0, 0);
    ra = ra2; rb = rb2; bp0 = bn0; bp1 = bn1;
  }

  float binv0 = b_in[lo];
  float binv1 = b_in[16 + lo];
  // D-frag: row = 16w + 4g + r, col = 16nt + lo  -> h into frag-direct LDS (bf16)
#pragma unroll
  for (int nt = 0; nt < 2; ++nt) {
#pragma unroll
    for (int r = 0; r < 4; ++r) {
      float hv = acc1[nt][r] + (nt ? binv1 : binv0);
      int cc = 2 * nt + (lo >> 3);
      int slotlane = (4 * g + r) | (cc << 4);
      lds_ho[w][slotlane][lo & 7] = f2bf(hv);
    }
  }
  __syncthreads();

  // ---------------- P2: q/k/v = h @ Wq/Wk/Wv  (6 MFMAs per wave) ----------------
  const bf16x8* __restrict__ wsWq = (const bf16x8*)(wsb + 32768);
  const bf16x8* __restrict__ wsWk = (const bf16x8*)(wsb + 33792);
  const bf16x8* __restrict__ wsWv = (const bf16x8*)(wsb + 34816);
  bf16x8 ah = *(const bf16x8*)&lds_ho[w][l][0];
  f32x4 qacc[2], kacc[2], vacc[2];
#pragma unroll
  for (int nt = 0; nt < 2; ++nt) {
    qacc[nt] = __builtin_amdgcn_mfma_f32_16x16x32_bf16(ah, wsWq[nt * 64 + l], zero4, 0, 0, 0);
    kacc[nt] = __builtin_amdgcn_mfma_f32_16x16x32_bf16(ah, wsWk[nt * 64 + l], zero4, 0, 0, 0);
    vacc[nt] = __builtin_amdgcn_mfma_f32_16x16x32_bf16(ah, wsWv[nt * 64 + l], zero4, 0, 0, 0);
  }
#pragma unroll
  for (int nt = 0; nt < 2; ++nt) {
#pragma unroll
    for (int r = 0; r < 4; ++r) {
      int row = 16 * w + 4 * g + r;
      int col = 16 * nt + lo;
      lds_q[row][col] = qacc[nt][r];
      lds_k[row][col] = kacc[nt][r];
      lds_v[row][col] = vacc[nt][r];
    }
  }
  __syncthreads();

  // ---------------- P3: attention, online no-max softmax ------------------------
  // thread = (channel c = lane, head = wave); scores |s| <~ 3 so exp2 is f32-safe
  {
    const int hd = w;
    const f32x4 qv0 = *(const f32x4*)&lds_q[l][8 * hd];
    const f32x4 qv1 = *(const f32x4*)&lds_q[l][8 * hd + 4];
    float sum = 0.f;
    float ov[8] = {0.f, 0.f, 0.f, 0.f, 0.f, 0.f, 0.f, 0.f};
#pragma unroll 4
    for (int kk = 0; kk < 64; ++kk) {
      f32x4 k0 = *(const f32x4*)&lds_k[kk][8 * hd];
      f32x4 k1 = *(const f32x4*)&lds_k[kk][8 * hd + 4];
      float s = qv0[0] * k0[0] + qv0[1] * k0[1] + qv0[2] * k0[2] + qv0[3] * k0[3]
              + qv1[0] * k1[0] + qv1[1] * k1[1] + qv1[2] * k1[2] + qv1[3] * k1[3];
      float p = exp2f(s * (1.4426950408889634f * 0.35355339059327373f));
      sum += p;
      f32x4 v0 = *(const f32x4*)&lds_v[kk][8 * hd];
      f32x4 v1 = *(const f32x4*)&lds_v[kk][8 * hd + 4];
      ov[0] += p * v0[0]; ov[1] += p * v0[1]; ov[2] += p * v0[2]; ov[3] += p * v0[3];
      ov[4] += p * v1[0]; ov[5] += p * v1[1]; ov[6] += p * v1[2]; ov[7] += p * v1[3];
    }
    float inv = 1.0f / sum;
    bf16x8 opk;
#pragma unroll
    for (int d = 0; d < 8; ++d) opk[d] = (short)f2bf(ov[d] * inv);
    // o[c][8hd+d] -> frag slot [c>>4][(c&15)|(hd<<4)][d]  (h is dead; reuse lds_ho)
    *(bf16x8*)&lds_ho[l >> 4][(l & 15) | (hd << 4)][0] = opk;
  }
  __syncthreads();

  // ---------------- P4: y = o @ W_out + b_out + x, LayerNorm (single pass) ------
  // wave w owns rows 16w..16w+15, ALL 512 cols; thread owns 4 rows (16w+4g+r).
  // y kept packed bf16 in registers: yp[nt][0]=rows 0,1  yp[nt][1]=rows 2,3.
  const bf16x8 a4 = *(const bf16x8*)&lds_ho[w][l][0];
  const bf16x8* __restrict__ wsWout = (const bf16x8*)(wsb + 16384);
  const int row0 = 16 * w + 4 * g;
  const float* __restrict__ xrow = xb + row0 * NT + lo;

  unsigned yp[32][2];
  float s1[4] = {0.f, 0.f, 0.f, 0.f};
  float s2[4] = {0.f, 0.f, 0.f, 0.f};

#pragma unroll
  for (int nt = 0; nt < 32; ++nt) {
    bf16x8 bfr = wsWout[nt * 64 + l];
    f32x4 acc = __builtin_amdgcn_mfma_f32_16x16x32_bf16(a4, bfr, zero4, 0, 0, 0);
    const int col = 16 * nt;
    float bo = b_out[col + lo];
    float y0 = acc[0] + bo + xrow[0 * NT + col];
    float y1 = acc[1] + bo + xrow[1 * NT + col];
    float y2 = acc[2] + bo + xrow[2 * NT + col];
    float y3 = acc[3] + bo + xrow[3 * NT + col];
    s1[0] += y0; s2[0] += y0 * y0;
    s1[1] += y1; s2[1] += y1 * y1;
    s1[2] += y2; s2[2] += y2 * y2;
    s1[3] += y3; s2[3] += y3 * y3;
    yp[nt][0] = (unsigned)f2bf(y0) | ((unsigned)f2bf(y1) << 16);
    yp[nt][1] = (unsigned)f2bf(y2) | ((unsigned)f2bf(y3) << 16);
    // fence scheduler every 4 iters: stop load hoisting from exploding liveness
    if ((nt & 3) == 3) __builtin_amdgcn_sched_barrier(0);
  }
  // LN reduce: each row's 512 cols live in the 16 lanes sharing g
#pragma unroll
  for (int off = 1; off <= 8; off <<= 1) {
#pragma unroll
    for (int r = 0; r < 4; ++r) {
      s1[r] += __shfl_xor(s1[r], off, 64);
      s2[r] += __shfl_xor(s2[r], off, 64);
    }
  }
  float mu[4], rs[4];
#pragma unroll
  for (int r = 0; r < 4; ++r) {
    mu[r] = s1[r] * (1.0f / 512.0f);
    float var = s2[r] * (1.0f / 512.0f) - mu[r] * mu[r];
    rs[r] = rsqrtf(var + 1e-5f);
  }

  // ---- pass 2: unpack, normalize, store (loads only gamma/beta, no MFMA) -------
  float* __restrict__ orow = out + (size_t)b * (NC * NT) + row0 * NT + lo;
#pragma unroll
  for (int nt = 0; nt < 32; ++nt) {
    const int col = 16 * nt;
    float gm = gamma[col + lo];
    float bt = beta[col + lo];
    float y0 = bf2f((unsigned short)(yp[nt][0] & 0xffffu));
    float y1 = bf2f((unsigned short)(yp[nt][0] >> 16));
    float y2 = bf2f((unsigned short)(yp[nt][1] & 0xffffu));
    float y3 = bf2f((unsigned short)(yp[nt][1] >> 16));
    orow[0 * NT + col] = (y0 - mu[0]) * rs[0] * gm + bt;
    orow[1 * NT + col] = (y1 - mu[1]) * rs[1] * gm + bt;
    orow[2 * NT + col] = (y2 - mu[2]) * rs[2] * gm + bt;
    orow[3 * NT + col] = (y3 - mu[3]) * rs[3] * gm + bt;
    if ((nt & 7) == 7) __builtin_amdgcn_sched_barrier(0);
  }
}

extern "C" void kernel_launch(void* const* d_in, const int* in_sizes, int n_in,
                              void* d_out, int out_size, void* d_ws, size_t ws_size,
                              hipStream_t stream) {
  const float* x     = (const float*)d_in[0];
  const float* W_in  = (const float*)d_in[1];
  const float* b_in  = (const float*)d_in[2];
  const float* W_q   = (const float*)d_in[3];
  const float* W_k   = (const float*)d_in[4];
  const float* W_v   = (const float*)d_in[5];
  const float* W_out = (const float*)d_in[6];
  const float* b_out = (const float*)d_in[7];
  const float* gamma = (const float*)d_in[8];
  const float* beta  = (const float*)d_in[9];
  unsigned short* ws = (unsigned short*)d_ws;

  prep_weights<<<140, 256, 0, stream>>>(W_in, W_q, W_k, W_v, W_out, ws);
  mha_main<<<NB, 256, 0, stream>>>(x, b_in, b_out, gamma, beta, ws, (float*)d_out);
}

// Round 9
// 89.356 us; speedup vs baseline: 1.7696x; 1.5335x over previous
//
#include <hip/hip_runtime.h>

typedef __attribute__((ext_vector_type(8))) short bf16x8;
typedef __attribute__((ext_vector_type(4))) float f32x4;

#define NB 1024
#define NC 64
#define NT 512
#define ND 32

__device__ __forceinline__ unsigned short f2bf(float f) {
  unsigned u = __float_as_uint(f);
  u += 0x7FFFu + ((u >> 16) & 1u);   // round-to-nearest-even (finite values)
  return (unsigned short)(u >> 16);
}
__device__ __forceinline__ float bf2f(unsigned short h) {
  return __uint_as_float(((unsigned)h) << 16);
}

// ---- prep: rearrange weights into MFMA B-fragment order (bf16) ----
// ws layout (ushort elements):
//   [0,16384)      Win  frags [ks(16)][nt(2)][lane(64)][j(8)]   B[k][n], k=32ks+8(l>>4)+j, n=16nt+(l&15)
//   [16384,32768)  Wout frags [nt(32)][lane(64)][j(8)]
//   [32768,33792)  Wq   frags [nt(2)][lane(64)][j(8)]
//   [33792,34816)  Wk   frags
//   [34816,35840)  Wv   frags
__global__ void prep_weights(const float* __restrict__ Win, const float* __restrict__ Wq,
                             const float* __restrict__ Wk, const float* __restrict__ Wv,
                             const float* __restrict__ Wout, unsigned short* __restrict__ ws) {
  int idx = blockIdx.x * 256 + threadIdx.x;
  if (idx >= 35840) return;
  float v;
  if (idx < 16384) {
    int j = idx & 7, lane = (idx >> 3) & 63, nt = (idx >> 9) & 1, ks = idx >> 10;
    int t = 32 * ks + 8 * (lane >> 4) + j;
    int d = 16 * nt + (lane & 15);
    v = Win[t * ND + d];
  } else if (idx < 32768) {
    int p = idx - 16384;
    int j = p & 7, lane = (p >> 3) & 63, nt = (p >> 9) & 31;
    int k = 8 * (lane >> 4) + j;
    int n = 16 * nt + (lane & 15);
    v = Wout[k * NT + n];
  } else {
    int p = idx - 32768;
    const float* W = (p < 1024) ? Wq : ((p < 2048) ? Wk : Wv);
    int q = p & 1023;
    int j = q & 7, lane = (q >> 3) & 63, nt = (q >> 9) & 1;
    int t = 8 * (lane >> 4) + j;
    int d = 16 * nt + (lane & 15);
    v = W[t * ND + d];
  }
  ws[idx] = f2bf(v);
}

// ---- fused main kernel: one block per batch, 256 threads (4 waves) ----
// Register budget: <=128 unified -> 4 waves/SIMD -> 4 blocks/CU.
// P3: online no-max softmax (scores |s|<~3, exp2 f32-safe) -> no score array.
// P4: SINGLE pass. y packed bf16 and stashed in 64 AGPRs via v_accvgpr_write
//     ("a" constraint) -- the AGPR half of the unified file is otherwise idle,
//     and R7/R8 proved 64 extra VGPRs don't fit (scratch spill, WRITE +100MB).
//     Pass 2 = accvgpr_read + normalize + store: no x re-read, no MFMA.
// LDS = 4096 (h/o frags) + 27648 (q/k/v f32) = 31744 B.
__global__ __launch_bounds__(256, 4)
void mha_main(const float* __restrict__ x, const float* __restrict__ b_in,
              const float* __restrict__ b_out, const float* __restrict__ gamma,
              const float* __restrict__ beta, const unsigned short* __restrict__ wsb,
              float* __restrict__ out) {
  __shared__ __align__(16) unsigned short lds_ho[4][64][8];  // h frags, then o frags
  __shared__ __align__(16) float lds_q[64][36];
  __shared__ __align__(16) float lds_k[64][36];
  __shared__ __align__(16) float lds_v[64][36];

  const int tid = threadIdx.x;
  const int w  = tid >> 6;   // wave id
  const int l  = tid & 63;   // lane
  const int g  = l >> 4;     // quarter-wave group
  const int lo = l & 15;
  const int b  = blockIdx.x;
  const float* __restrict__ xb = x + (size_t)b * (NC * NT);

  // ---------------- P1: h = x @ W_in + b_in  (A-frags loaded from global) -------
  const int srow = 16 * w + lo;
  const float* __restrict__ xr = xb + srow * NT + 8 * g;
  const bf16x8* __restrict__ wsWin = (const bf16x8*)wsb;

  f32x4 zero4 = (f32x4){0.f, 0.f, 0.f, 0.f};
  f32x4 acc1[2];
  acc1[0] = zero4;
  acc1[1] = zero4;
  f32x4 ra = *(const f32x4*)(xr);
  f32x4 rb = *(const f32x4*)(xr + 4);
  bf16x8 bp0 = wsWin[l];
  bf16x8 bp1 = wsWin[64 + l];

#pragma unroll
  for (int ks = 0; ks < 16; ++ks) {
    bf16x8 af;
    af[0] = (short)f2bf(ra[0]); af[1] = (short)f2bf(ra[1]);
    af[2] = (short)f2bf(ra[2]); af[3] = (short)f2bf(ra[3]);
    af[4] = (short)f2bf(rb[0]); af[5] = (short)f2bf(rb[1]);
    af[6] = (short)f2bf(rb[2]); af[7] = (short)f2bf(rb[3]);
    int nk = (ks < 15) ? (ks + 1) : 15;   // prefetch next chunk (clamped)
    f32x4 ra2 = *(const f32x4*)(xr + 32 * nk);
    f32x4 rb2 = *(const f32x4*)(xr + 32 * nk + 4);
    bf16x8 bn0 = wsWin[(2 * nk) * 64 + l];
    bf16x8 bn1 = wsWin[(2 * nk + 1) * 64 + l];
    acc1[0] = __builtin_amdgcn_mfma_f32_16x16x32_bf16(af, bp0, acc1[0], 0, 0, 0);
    acc1[1] = __builtin_amdgcn_mfma_f32_16x16x32_bf16(af, bp1, acc1[1], 0, 0, 0);
    ra = ra2; rb = rb2; bp0 = bn0; bp1 = bn1;
  }

  float binv0 = b_in[lo];
  float binv1 = b_in[16 + lo];
  // D-frag: row = 16w + 4g + r, col = 16nt + lo  -> h into frag-direct LDS (bf16)
#pragma unroll
  for (int nt = 0; nt < 2; ++nt) {
#pragma unroll
    for (int r = 0; r < 4; ++r) {
      float hv = acc1[nt][r] + (nt ? binv1 : binv0);
      int cc = 2 * nt + (lo >> 3);
      int slotlane = (4 * g + r) | (cc << 4);
      lds_ho[w][slotlane][lo & 7] = f2bf(hv);
    }
  }
  __syncthreads();

  // ---------------- P2: q/k/v = h @ Wq/Wk/Wv  (6 MFMAs per wave) ----------------
  const bf16x8* __restrict__ wsWq = (const bf16x8*)(wsb + 32768);
  const bf16x8* __restrict__ wsWk = (const bf16x8*)(wsb + 33792);
  const bf16x8* __restrict__ wsWv = (const bf16x8*)(wsb + 34816);
  bf16x8 ah = *(const bf16x8*)&lds_ho[w][l][0];
  f32x4 qacc[2], kacc[2], vacc[2];
#pragma unroll
  for (int nt = 0; nt < 2; ++nt) {
    qacc[nt] = __builtin_amdgcn_mfma_f32_16x16x32_bf16(ah, wsWq[nt * 64 + l], zero4, 0, 0, 0);
    kacc[nt] = __builtin_amdgcn_mfma_f32_16x16x32_bf16(ah, wsWk[nt * 64 + l], zero4, 0, 0, 0);
    vacc[nt] = __builtin_amdgcn_mfma_f32_16x16x32_bf16(ah, wsWv[nt * 64 + l], zero4, 0, 0, 0);
  }
#pragma unroll
  for (int nt = 0; nt < 2; ++nt) {
#pragma unroll
    for (int r = 0; r < 4; ++r) {
      int row = 16 * w + 4 * g + r;
      int col = 16 * nt + lo;
      lds_q[row][col] = qacc[nt][r];
      lds_k[row][col] = kacc[nt][r];
      lds_v[row][col] = vacc[nt][r];
    }
  }
  __syncthreads();

  // ---------------- P3: attention, online no-max softmax ------------------------
  // thread = (channel c = lane, head = wave); scores |s| <~ 3 so exp2 is f32-safe
  {
    const int hd = w;
    const f32x4 qv0 = *(const f32x4*)&lds_q[l][8 * hd];
    const f32x4 qv1 = *(const f32x4*)&lds_q[l][8 * hd + 4];
    float sum = 0.f;
    float ov[8] = {0.f, 0.f, 0.f, 0.f, 0.f, 0.f, 0.f, 0.f};
#pragma unroll 4
    for (int kk = 0; kk < 64; ++kk) {
      f32x4 k0 = *(const f32x4*)&lds_k[kk][8 * hd];
      f32x4 k1 = *(const f32x4*)&lds_k[kk][8 * hd + 4];
      float s = qv0[0] * k0[0] + qv0[1] * k0[1] + qv0[2] * k0[2] + qv0[3] * k0[3]
              + qv1[0] * k1[0] + qv1[1] * k1[1] + qv1[2] * k1[2] + qv1[3] * k1[3];
      float p = exp2f(s * (1.4426950408889634f * 0.35355339059327373f));
      sum += p;
      f32x4 v0 = *(const f32x4*)&lds_v[kk][8 * hd];
      f32x4 v1 = *(const f32x4*)&lds_v[kk][8 * hd + 4];
      ov[0] += p * v0[0]; ov[1] += p * v0[1]; ov[2] += p * v0[2]; ov[3] += p * v0[3];
      ov[4] += p * v1[0]; ov[5] += p * v1[1]; ov[6] += p * v1[2]; ov[7] += p * v1[3];
    }
    float inv = 1.0f / sum;
    bf16x8 opk;
#pragma unroll
    for (int d = 0; d < 8; ++d) opk[d] = (short)f2bf(ov[d] * inv);
    // o[c][8hd+d] -> frag slot [c>>4][(c&15)|(hd<<4)][d]  (h is dead; reuse lds_ho)
    *(bf16x8*)&lds_ho[l >> 4][(l & 15) | (hd << 4)][0] = opk;
  }
  __syncthreads();

  // ---------------- P4: y = o @ W_out + b_out + x, LayerNorm (single pass) ------
  // wave w owns rows 16w..16w+15, ALL 512 cols; thread owns 4 rows (16w+4g+r).
  // y packed bf16: ag0[nt]=rows 0,1  ag1[nt]=rows 2,3 -- PINNED TO AGPRs.
  const bf16x8 a4 = *(const bf16x8*)&lds_ho[w][l][0];
  const bf16x8* __restrict__ wsWout = (const bf16x8*)(wsb + 16384);
  const int row0 = 16 * w + 4 * g;
  const float* __restrict__ xrow = xb + row0 * NT + lo;

  unsigned ag0[32], ag1[32];   // fully unrolled -> SSA scalars in AGPR class
  float s1[4] = {0.f, 0.f, 0.f, 0.f};
  float s2[4] = {0.f, 0.f, 0.f, 0.f};

#pragma unroll
  for (int nt = 0; nt < 32; ++nt) {
    bf16x8 bfr = wsWout[nt * 64 + l];
    f32x4 acc = __builtin_amdgcn_mfma_f32_16x16x32_bf16(a4, bfr, zero4, 0, 0, 0);
    const int col = 16 * nt;
    float bo = b_out[col + lo];
    float y0 = acc[0] + bo + xrow[0 * NT + col];
    float y1 = acc[1] + bo + xrow[1 * NT + col];
    float y2 = acc[2] + bo + xrow[2 * NT + col];
    float y3 = acc[3] + bo + xrow[3 * NT + col];
    s1[0] += y0; s2[0] += y0 * y0;
    s1[1] += y1; s2[1] += y1 * y1;
    s1[2] += y2; s2[2] += y2 * y2;
    s1[3] += y3; s2[3] += y3 * y3;
    unsigned p0 = (unsigned)f2bf(y0) | ((unsigned)f2bf(y1) << 16);
    unsigned p1 = (unsigned)f2bf(y2) | ((unsigned)f2bf(y3) << 16);
    asm("v_accvgpr_write_b32 %0, %1" : "=a"(ag0[nt]) : "v"(p0));
    asm("v_accvgpr_write_b32 %0, %1" : "=a"(ag1[nt]) : "v"(p1));
    // fence scheduler every 4 iters: stop load hoisting from exploding liveness
    if ((nt & 3) == 3) __builtin_amdgcn_sched_barrier(0);
  }
  // LN reduce: each row's 512 cols live in the 16 lanes sharing g
#pragma unroll
  for (int off = 1; off <= 8; off <<= 1) {
#pragma unroll
    for (int r = 0; r < 4; ++r) {
      s1[r] += __shfl_xor(s1[r], off, 64);
      s2[r] += __shfl_xor(s2[r], off, 64);
    }
  }
  float mu[4], rs[4];
#pragma unroll
  for (int r = 0; r < 4; ++r) {
    mu[r] = s1[r] * (1.0f / 512.0f);
    float var = s2[r] * (1.0f / 512.0f) - mu[r] * mu[r];
    rs[r] = rsqrtf(var + 1e-5f);
  }

  // ---- pass 2: accvgpr_read, normalize, store (only gamma/beta loads) ----------
  float* __restrict__ orow = out + (size_t)b * (NC * NT) + row0 * NT + lo;
#pragma unroll
  for (int nt = 0; nt < 32; ++nt) {
    const int col = 16 * nt;
    float gm = gamma[col + lo];
    float bt = beta[col + lo];
    unsigned p0, p1;
    asm("v_accvgpr_read_b32 %0, %1" : "=v"(p0) : "a"(ag0[nt]));
    asm("v_accvgpr_read_b32 %0, %1" : "=v"(p1) : "a"(ag1[nt]));
    float y0 = bf2f((unsigned short)(p0 & 0xffffu));
    float y1 = bf2f((unsigned short)(p0 >> 16));
    float y2 = bf2f((unsigned short)(p1 & 0xffffu));
    float y3 = bf2f((unsigned short)(p1 >> 16));
    orow[0 * NT + col] = (y0 - mu[0]) * rs[0] * gm + bt;
    orow[1 * NT + col] = (y1 - mu[1]) * rs[1] * gm + bt;
    orow[2 * NT + col] = (y2 - mu[2]) * rs[2] * gm + bt;
    orow[3 * NT + col] = (y3 - mu[3]) * rs[3] * gm + bt;
    if ((nt & 7) == 7) __builtin_amdgcn_sched_barrier(0);
  }
}

extern "C" void kernel_launch(void* const* d_in, const int* in_sizes, int n_in,
                              void* d_out, int out_size, void* d_ws, size_t ws_size,
                              hipStream_t stream) {
  const float* x     = (const float*)d_in[0];
  const float* W_in  = (const float*)d_in[1];
  const float* b_in  = (const float*)d_in[2];
  const float* W_q   = (const float*)d_in[3];
  const float* W_k   = (const float*)d_in[4];
  const float* W_v   = (const float*)d_in[5];
  const float* W_out = (const float*)d_in[6];
  const float* b_out = (const float*)d_in[7];
  const float* gamma = (const float*)d_in[8];
  const float* beta  = (const float*)d_in[9];
  unsigned short* ws = (unsigned short*)d_ws;

  prep_weights<<<140, 256, 0, stream>>>(W_in, W_q, W_k, W_v, W_out, ws);
  mha_main<<<NB, 256, 0, stream>>>(x, b_in, b_out, gamma, beta, ws, (float*)d_out);
}